// Round 7
// baseline (223.403 us; speedup 1.0000x reference)
//
#include <hip/hip_runtime.h>
#include <stdint.h>

typedef unsigned short u16;
typedef __bf16    bf16x8 __attribute__((ext_vector_type(8)));
typedef u16       u16x8  __attribute__((ext_vector_type(8)));
typedef u16       u16x4  __attribute__((ext_vector_type(4)));
typedef float     f32x4  __attribute__((ext_vector_type(4)));
typedef uint32_t  u32x4  __attribute__((ext_vector_type(4)));

#define MFMA16x16x32(a, b, c) __builtin_amdgcn_mfma_f32_16x16x32_bf16((a), (b), (c), 0, 0, 0)

__device__ __forceinline__ u16 f2bf(float f) {
  uint32_t u = __float_as_uint(f);
  u += 0x7FFFu + ((u >> 16) & 1u);   // RNE
  return (u16)(u >> 16);
}

// pack hi16(a), hi16(b) -> one dword via v_perm (truncation toward zero; p>=0)
__device__ __forceinline__ uint32_t pktrunc(float a, float b) {
  return __builtin_amdgcn_perm(__float_as_uint(b), __float_as_uint(a), 0x07060302u);
}

__device__ __forceinline__ bf16x8 ldfrag(const u16* p) {
  return __builtin_bit_cast(bf16x8, *(const u16x8*)p);
}

// 16B fragment from two 8B LDS reads (8B-aligned, bank-clean at stride 68)
__device__ __forceinline__ bf16x8 ldfrag2(const u16* p) {
  uint2 a = *(const uint2*)p;
  uint2 b = *(const uint2*)(p + 4);
  u32x4 t; t[0] = a.x; t[1] = a.y; t[2] = b.x; t[3] = b.y;
  return __builtin_bit_cast(bf16x8, t);
}

// async global->LDS, 16B per lane. LDS dest must be wave-uniform base + lane*16.
__device__ __forceinline__ void gl2lds16(const u16* g, u16* l) {
  __builtin_amdgcn_global_load_lds(
      (__attribute__((address_space(1))) void*)g,
      (__attribute__((address_space(3))) void*)l, 16, 0, 0);
}

// ---------------- fp32 -> bf16 conversion of x, Wqkv, Wout ----------------
__global__ __launch_bounds__(256) void convert3(
    const float* __restrict__ x, const float* __restrict__ wq,
    const float* __restrict__ wo, u16* __restrict__ xb,
    u16* __restrict__ wqb, u16* __restrict__ wob) {
  const int NX = (4096 * 1024) / 8;
  const int NQ = (3072 * 1024) / 8;
  int i = blockIdx.x * 256 + threadIdx.x;   // exactly covers NX+NQ+NO
  const float* s;
  u16* d;
  if (i < NX)           { s = x;  d = xb;  }
  else if (i < NX + NQ) { s = wq; d = wqb; i -= NX; }
  else                  { s = wo; d = wob; i -= NX + NQ; }
  f32x4 a = ((const f32x4*)s)[2 * (size_t)i];
  f32x4 b = ((const f32x4*)s)[2 * (size_t)i + 1];
  u16x8 r;
  #pragma unroll
  for (int e = 0; e < 4; ++e) { r[e] = f2bf(a[e]); r[4 + e] = f2bf(b[e]); }
  ((u16x8*)d)[i] = r;
}

// ---------------- QKV projection: C[4096,3072] = X * Wqkv^T + b ----------------
// BK=64, XOR chunk-swizzled LDS, swapped-operand MFMA (C^T: lane regs = 4
// consecutive n = d) -> u16x4 epilogue stores. Q scaled 0.125; (b,h,s,d).
__global__ __launch_bounds__(256) void qkv_gemm(
    const u16* __restrict__ A, const u16* __restrict__ Bw,
    const float* __restrict__ bias, u16* __restrict__ Qo,
    u16* __restrict__ Ko, u16* __restrict__ Vo) {
  __shared__ __align__(16) u16 As[128 * 64];
  __shared__ __align__(16) u16 Bs[128 * 64];

  const int t = threadIdx.x;
  const int lane = t & 63, w = t >> 6;
  const int quad = lane >> 4, col = lane & 15;
  const int wm = w & 1, wn = w >> 1;
  const int m0 = blockIdx.y * 128, n0 = blockIdx.x * 128;

  f32x4 acc[4][4] = {};

  for (int kt = 0; kt < 16; ++kt) {
    const int ko = kt * 64;
    __syncthreads();
    #pragma unroll
    for (int p = 0; p < 4; ++p) {
      int c = t + 256 * p;                  // 0..1023
      int r = c >> 3, cc = c & 7;
      int so = ko + ((cc ^ (r & 7)) * 8);
      gl2lds16(A  + (size_t)(m0 + r) * 1024 + so, As + c * 8);
      gl2lds16(Bw + (size_t)(n0 + r) * 1024 + so, Bs + c * 8);
    }
    __syncthreads();

    #pragma unroll
    for (int kk = 0; kk < 2; ++kk) {
      const int e8 = ((kk * 4 + quad) ^ (col & 7)) * 8;
      bf16x8 bfr[4];
      #pragma unroll
      for (int j = 0; j < 4; ++j)
        bfr[j] = ldfrag(Bs + (wn * 64 + j * 16 + col) * 64 + e8);
      #pragma unroll
      for (int i = 0; i < 4; ++i) {
        bf16x8 afr = ldfrag(As + (wm * 64 + i * 16 + col) * 64 + e8);
        #pragma unroll
        for (int j = 0; j < 4; ++j)
          acc[i][j] = MFMA16x16x32(bfr[j], afr, acc[i][j]);  // C^T
      }
    }
  }

  const int nb = n0 + wn * 64;              // wave covers one 64-wide head slice
  const int which = nb >> 10;               // 0=q 1=k 2=v (wave-uniform)
  const int h = (nb >> 6) & 15;
  u16* dst = (which == 0) ? Qo : ((which == 1) ? Ko : Vo);
  const float scale = (which == 0) ? 0.125f : 1.0f;

  #pragma unroll
  for (int j = 0; j < 4; ++j) {
    const f32x4 b4 = *(const f32x4*)(bias + nb + j * 16 + quad * 4);
    #pragma unroll
    for (int i = 0; i < 4; ++i) {
      const int m = m0 + wm * 64 + i * 16 + col;
      const int bb = m >> 11, s = m & 2047;
      u16x4 vv;
      #pragma unroll
      for (int r = 0; r < 4; ++r) vv[r] = f2bf((acc[i][j][r] + b4[r]) * scale);
      *(u16x4*)(dst + ((size_t)(bb * 16 + h) * 2048 + s) * 64 + j * 16 + quad * 4) = vv;
    }
  }
}

// ---------------- V (b,h,s,d) -> Vt (b,h,d,s) 64x64-tile transpose ----------------
__global__ __launch_bounds__(256) void transpose64(
    const u16* __restrict__ V, u16* __restrict__ Vt) {
  __shared__ u16 tile[64][72];
  const int t = threadIdx.x;
  const int s0 = blockIdx.x * 64;
  const int bh = blockIdx.y;
  const u16* Vb = V + (size_t)bh * (2048 * 64);
  u16* Vtb = Vt + (size_t)bh * (64 * 2048);
  #pragma unroll
  for (int p = 0; p < 2; ++p) {
    int c = t + 256 * p;
    int r = c >> 3, c8 = (c & 7) * 8;
    u16x8 v = *(const u16x8*)(Vb + (size_t)(s0 + r) * 64 + c8);
    #pragma unroll
    for (int e = 0; e < 8; ++e) tile[r][c8 + e] = v[e];
  }
  __syncthreads();
  #pragma unroll
  for (int p = 0; p < 2; ++p) {
    int c = t + 256 * p;
    int dr = c >> 3, c8 = (c & 7) * 8;
    u16x8 v;
    #pragma unroll
    for (int e = 0; e < 8; ++e) v[e] = tile[c8 + e][dr];
    *(u16x8*)(Vtb + (size_t)dr * 2048 + s0 + c8) = v;
  }
}

// ---------------- fused attention (S^T, fat waves, split-K, pipelined) ----------------
// 512 threads = 8 fat waves (32 q each; wave pair u shares q, g = key half).
// Single barrier per 128-key tile: Ks ping-pong staged async for kb+1 while
// computing kb; V^T fragments read DIRECT from global (16KB tile, L1-resident,
// shared by the 4 wave-pairs). Iter order: mask->regs, sched_barrier, stage(kb+1),
// S^T (LDS only, no vmem wait), softmax, PV (av gated on staging ~done by now).
// Grid (bh=32, qb=16): same-bh blocks land on one XCD -> K/V L2-pinned.
__global__ __launch_bounds__(512, 4) void attn(
    const u16* __restrict__ Q, const u16* __restrict__ K,
    const u16* __restrict__ Vt, const int* __restrict__ mask,
    u16* __restrict__ AO) {
  __shared__ __align__(16) u16 Ks[2][128 * 64];  // ping-pong [key][d], XOR swizzle
  __shared__ __align__(16) u16 Ps[8][32 * 68];   // per-wave P^T (64 keys), stride 68

  const int t = threadIdx.x;
  const int lane = t & 63, w = t >> 6;
  const int quad = lane >> 4, col = lane & 15;
  const int g = w & 1, u = w >> 1;
  const int bh = blockIdx.x, qb = blockIdx.y;
  const int b = bh >> 4, h = bh & 15;

  const u16* Qh = Q + (size_t)bh * (2048 * 64);
  const u16* Kh = K + (size_t)bh * (2048 * 64);
  const u16* Vh = Vt + (size_t)bh * (64 * 2048);
  const int* mb = mask + b * 2048;

  u16x8 ou;
  #pragma unroll
  for (int e = 0; e < 8; ++e) ou[e] = 0x3F80;    // bf16 1.0
  const bf16x8 ones = __builtin_bit_cast(bf16x8, ou);

  const int qw = qb * 128 + u * 32;              // wave-pair's first q
  const int keyg = g * 64;                       // this wave's key half
  const u16* Vl = Vh + (size_t)col * 2048 + keyg + quad * 8;

  bf16x8 aQ[2][2];
  #pragma unroll
  for (int ct = 0; ct < 2; ++ct) {
    #pragma unroll
    for (int kh = 0; kh < 2; ++kh)
      aQ[ct][kh] = ldfrag(Qh + (size_t)(qw + ct * 16 + col) * 64 + kh * 32 + quad * 8);
  }

  f32x4 o[2][4] = {};
  f32x4 lacc[2] = {};
  u16* Pw = &Ps[w][0];

  // prologue: stage tile 0
  #pragma unroll
  for (int p = 0; p < 2; ++p) {
    int c = t + 512 * p;
    int kr = c >> 3, kc = c & 7;
    gl2lds16(Kh + (size_t)kr * 64 + ((kc ^ (kr & 7)) * 8), &Ks[0][0] + c * 8);
  }
  __syncthreads();

  for (int kb = 0; kb < 16; ++kb) {
    const int key0 = kb * 128;
    const u16* cur = &Ks[kb & 1][0];

    // 1) mask -> packed AND-masks in registers (before staging: no vmcnt chain)
    uint32_t M[4][2];
    #pragma unroll
    for (int jj = 0; jj < 4; ++jj) {
      int4 m4 = *(const int4*)(mb + key0 + keyg + jj * 16 + quad * 4);
      M[jj][0] = (m4.x ? 0x0000FFFFu : 0u) | (m4.y ? 0xFFFF0000u : 0u);
      M[jj][1] = (m4.z ? 0x0000FFFFu : 0u) | (m4.w ? 0xFFFF0000u : 0u);
    }
    __builtin_amdgcn_sched_barrier(0);

    // 2) async-stage next K tile into the other buffer
    if (kb < 15) {
      u16* nxt = &Ks[(kb + 1) & 1][0];
      #pragma unroll
      for (int p = 0; p < 2; ++p) {
        int c = t + 512 * p;
        int kr = c >> 3, kc = c & 7;
        gl2lds16(Kh + (size_t)(key0 + 128 + kr) * 64 + ((kc ^ (kr & 7)) * 8), nxt + c * 8);
      }
    }

    // 3) S^T = K Q^T (LDS reads only -> no vmem wait; overlaps staging flight)
    f32x4 sc[2][4] = {};
    #pragma unroll
    for (int j = 0; j < 4; ++j) {
      #pragma unroll
      for (int kh = 0; kh < 2; ++kh) {
        bf16x8 ak = ldfrag(cur + (keyg + j * 16 + col) * 64 + (((kh * 4 + quad) ^ (col & 7)) * 8));
        sc[0][j] = MFMA16x16x32(ak, aQ[0][kh], sc[0][j]);
        sc[1][j] = MFMA16x16x32(ak, aQ[1][kh], sc[1][j]);
      }
    }

    // 4) softmax numerators -> Ps (truncation-packed, masked; all register/LDS)
    #pragma unroll
    for (int jj = 0; jj < 4; ++jj) {
      #pragma unroll
      for (int ct = 0; ct < 2; ++ct) {
        uint2 pk;
        pk.x = pktrunc(__expf(sc[ct][jj][0]), __expf(sc[ct][jj][1])) & M[jj][0];
        pk.y = pktrunc(__expf(sc[ct][jj][2]), __expf(sc[ct][jj][3])) & M[jj][1];
        *(uint2*)(Pw + (ct * 16 + col) * 68 + jj * 16 + quad * 4) = pk;
      }
    }

    // 5) O^T += V^T P^T (V direct from global/L1); l += ones * P^T
    #pragma unroll
    for (int jp = 0; jp < 2; ++jp) {
      bf16x8 bP0 = ldfrag2(Pw + col * 68 + jp * 32 + quad * 8);
      bf16x8 bP1 = ldfrag2(Pw + (16 + col) * 68 + jp * 32 + quad * 8);
      lacc[0] = MFMA16x16x32(ones, bP0, lacc[0]);
      lacc[1] = MFMA16x16x32(ones, bP1, lacc[1]);
      #pragma unroll
      for (int dt = 0; dt < 4; ++dt) {
        bf16x8 av = ldfrag(Vl + dt * 32768 + key0 + jp * 32);
        o[0][dt] = MFMA16x16x32(av, bP0, o[0][dt]);
        o[1][dt] = MFMA16x16x32(av, bP1, o[1][dt]);
      }
    }

    __syncthreads();   // drains staging; protects Ks[cur] reuse + Ps for reduce
  }

  // combine wave-pair partials (additive: no online-max rescaling exists)
  float* Rb = (float*)(&Ps[0][0]);
  float* Ro = Rb + u * 2048 + lane * 32;         // 32 f32/lane, 16B-aligned
  float* Rl = Rb + 8192 + u * 128 + lane * 2;
  if (g == 1) {
    #pragma unroll
    for (int ct = 0; ct < 2; ++ct)
      #pragma unroll
      for (int dt = 0; dt < 4; ++dt)
        *(f32x4*)(Ro + ((ct * 4 + dt) ^ (lane & 7)) * 4) = o[ct][dt];
    Rl[0] = lacc[0][0]; Rl[1] = lacc[1][0];
  }
  __syncthreads();
  if (g == 0) {
    float rl[2];
    #pragma unroll
    for (int ct = 0; ct < 2; ++ct) {
      #pragma unroll
      for (int dt = 0; dt < 4; ++dt)
        o[ct][dt] += *(const f32x4*)(Ro + ((ct * 4 + dt) ^ (lane & 7)) * 4);
      rl[ct] = 1.0f / (lacc[ct][0] + Rl[ct]);
    }
    #pragma unroll
    for (int ct = 0; ct < 2; ++ct) {
      const int q = qw + ct * 16 + col;
      #pragma unroll
      for (int dt = 0; dt < 4; ++dt) {
        u16x4 v;
        #pragma unroll
        for (int r = 0; r < 4; ++r) v[r] = f2bf(o[ct][dt][r] * rl[ct]);
        *(u16x4*)(AO + (size_t)(b * 2048 + q) * 1024 + h * 64 + dt * 16 + quad * 4) = v;
      }
    }
  }
}

// ---------------- output projection: out = AO * Wout^T + bout (fp32 out) ----------------
// 128m x 64n tile (grid 512 -> 2 blocks/CU), BK=64 ping-pong, ONE barrier/iter.
__global__ __launch_bounds__(256) void proj_gemm(
    const u16* __restrict__ A, const u16* __restrict__ Bw,
    const float* __restrict__ bias, float* __restrict__ out) {
  __shared__ __align__(16) u16 As[2][128 * 64];
  __shared__ __align__(16) u16 Bs[2][64 * 64];

  const int t = threadIdx.x;
  const int lane = t & 63, w = t >> 6;
  const int quad = lane >> 4, col = lane & 15;
  const int wm = w & 1, wn = w >> 1;
  const int m0 = blockIdx.y * 128, n0 = blockIdx.x * 64;

  f32x4 acc[4][2] = {};

  // prologue: stage kt=0
  #pragma unroll
  for (int p = 0; p < 4; ++p) {
    int c = t + 256 * p;
    int r = c >> 3, cc = c & 7;
    gl2lds16(A + (size_t)(m0 + r) * 1024 + ((cc ^ (r & 7)) * 8), &As[0][0] + c * 8);
  }
  #pragma unroll
  for (int p = 0; p < 2; ++p) {
    int c = t + 256 * p;
    int r = c >> 3, cc = c & 7;
    gl2lds16(Bw + (size_t)(n0 + r) * 1024 + ((cc ^ (r & 7)) * 8), &Bs[0][0] + c * 8);
  }
  __syncthreads();

  for (int kt = 0; kt < 16; ++kt) {
    const u16* Ac = &As[kt & 1][0];
    const u16* Bc = &Bs[kt & 1][0];
    if (kt < 15) {
      const int ko = (kt + 1) * 64;
      u16* An = &As[(kt + 1) & 1][0];
      u16* Bn = &Bs[(kt + 1) & 1][0];
      #pragma unroll
      for (int p = 0; p < 4; ++p) {
        int c = t + 256 * p;
        int r = c >> 3, cc = c & 7;
        gl2lds16(A + (size_t)(m0 + r) * 1024 + ko + ((cc ^ (r & 7)) * 8), An + c * 8);
      }
      #pragma unroll
      for (int p = 0; p < 2; ++p) {
        int c = t + 256 * p;
        int r = c >> 3, cc = c & 7;
        gl2lds16(Bw + (size_t)(n0 + r) * 1024 + ko + ((cc ^ (r & 7)) * 8), Bn + c * 8);
      }
    }

    #pragma unroll
    for (int kk = 0; kk < 2; ++kk) {
      const int e8 = ((kk * 4 + quad) ^ (col & 7)) * 8;
      bf16x8 bfr[2];
      #pragma unroll
      for (int j = 0; j < 2; ++j)
        bfr[j] = ldfrag(Bc + (wn * 32 + j * 16 + col) * 64 + e8);
      #pragma unroll
      for (int i = 0; i < 4; ++i) {
        bf16x8 afr = ldfrag(Ac + (wm * 64 + i * 16 + col) * 64 + e8);
        #pragma unroll
        for (int j = 0; j < 2; ++j)
          acc[i][j] = MFMA16x16x32(bfr[j], afr, acc[i][j]);  // C^T
      }
    }
    __syncthreads();
  }

  const int nb = n0 + wn * 32;
  #pragma unroll
  for (int j = 0; j < 2; ++j) {
    const f32x4 b4 = *(const f32x4*)(bias + nb + j * 16 + quad * 4);
    #pragma unroll
    for (int i = 0; i < 4; ++i) {
      const int m = m0 + wm * 64 + i * 16 + col;
      f32x4 vv = acc[i][j] + b4;
      *(f32x4*)(out + (size_t)m * 1024 + nb + j * 16 + quad * 4) = vv;
    }
  }
}

extern "C" void kernel_launch(void* const* d_in, const int* in_sizes, int n_in,
                              void* d_out, int out_size, void* d_ws, size_t ws_size,
                              hipStream_t stream) {
  (void)in_sizes; (void)n_in; (void)out_size; (void)ws_size;
  const float* x    = (const float*)d_in[0];
  const int*   mask = (const int*)d_in[1];
  const float* Wqkv = (const float*)d_in[2];
  const float* bqkv = (const float*)d_in[3];
  const float* Wout = (const float*)d_in[4];
  const float* bout = (const float*)d_in[5];
  float* out = (float*)d_out;
  char* ws = (char*)d_ws;

  u16* Xb  = (u16*)(ws);                         // 8 MiB (reused as AO later)
  u16* Wqb = (u16*)(ws + ((size_t)8  << 20));    // 6 MiB
  u16* Wob = (u16*)(ws + ((size_t)14 << 20));    // 2 MiB
  u16* Qb  = (u16*)(ws + ((size_t)16 << 20));    // 8 MiB
  u16* Kb  = (u16*)(ws + ((size_t)24 << 20));    // 8 MiB
  u16* Vb  = (u16*)(ws + ((size_t)32 << 20));    // 8 MiB
  u16* Vtb = (u16*)(ws + ((size_t)40 << 20));    // 8 MiB  (total 48 MiB)
  u16* AO  = Xb;  // X is dead after qkv_gemm

  convert3<<<dim3(4096), dim3(256), 0, stream>>>(x, Wqkv, Wout, Xb, Wqb, Wob);
  qkv_gemm<<<dim3(24, 32), dim3(256), 0, stream>>>(Xb, Wqb, bqkv, Qb, Kb, Vb);
  transpose64<<<dim3(32, 32), dim3(256), 0, stream>>>(Vb, Vtb);
  attn<<<dim3(32, 16), dim3(512), 0, stream>>>(Qb, Kb, Vtb, mask, AO);
  proj_gemm<<<dim3(16, 32), dim3(256), 0, stream>>>(AO, Wob, bout, out);
}

// Round 8
// 206.960 us; speedup vs baseline: 1.0794x; 1.0794x over previous
//
#include <hip/hip_runtime.h>
#include <stdint.h>

typedef unsigned short u16;
typedef __bf16    bf16x8 __attribute__((ext_vector_type(8)));
typedef u16       u16x8  __attribute__((ext_vector_type(8)));
typedef u16       u16x4  __attribute__((ext_vector_type(4)));
typedef float     f32x4  __attribute__((ext_vector_type(4)));
typedef uint32_t  u32x4  __attribute__((ext_vector_type(4)));

#define MFMA16x16x32(a, b, c) __builtin_amdgcn_mfma_f32_16x16x32_bf16((a), (b), (c), 0, 0, 0)

__device__ __forceinline__ u16 f2bf(float f) {
  uint32_t u = __float_as_uint(f);
  u += 0x7FFFu + ((u >> 16) & 1u);   // RNE
  return (u16)(u >> 16);
}

// pack hi16(a), hi16(b) -> one dword via v_perm (truncation toward zero; p>=0)
__device__ __forceinline__ uint32_t pktrunc(float a, float b) {
  return __builtin_amdgcn_perm(__float_as_uint(b), __float_as_uint(a), 0x07060302u);
}

__device__ __forceinline__ bf16x8 ldfrag(const u16* p) {
  return __builtin_bit_cast(bf16x8, *(const u16x8*)p);
}

// fragment from two separate 8B LDS reads (XOR-swizzled chunks)
__device__ __forceinline__ bf16x8 ldfrag2b(const u16* p0, const u16* p1) {
  uint2 a = *(const uint2*)p0;
  uint2 b = *(const uint2*)p1;
  u32x4 t; t[0] = a.x; t[1] = a.y; t[2] = b.x; t[3] = b.y;
  return __builtin_bit_cast(bf16x8, t);
}

// async global->LDS, 16B per lane. LDS dest must be wave-uniform base + lane*16.
__device__ __forceinline__ void gl2lds16(const u16* g, u16* l) {
  __builtin_amdgcn_global_load_lds(
      (__attribute__((address_space(1))) void*)g,
      (__attribute__((address_space(3))) void*)l, 16, 0, 0);
}

// ---------------- fp32 -> bf16 conversion of x, Wqkv, Wout ----------------
__global__ __launch_bounds__(256) void convert3(
    const float* __restrict__ x, const float* __restrict__ wq,
    const float* __restrict__ wo, u16* __restrict__ xb,
    u16* __restrict__ wqb, u16* __restrict__ wob) {
  const int NX = (4096 * 1024) / 8;
  const int NQ = (3072 * 1024) / 8;
  int i = blockIdx.x * 256 + threadIdx.x;   // exactly covers NX+NQ+NO
  const float* s;
  u16* d;
  if (i < NX)           { s = x;  d = xb;  }
  else if (i < NX + NQ) { s = wq; d = wqb; i -= NX; }
  else                  { s = wo; d = wob; i -= NX + NQ; }
  f32x4 a = ((const f32x4*)s)[2 * (size_t)i];
  f32x4 b = ((const f32x4*)s)[2 * (size_t)i + 1];
  u16x8 r;
  #pragma unroll
  for (int e = 0; e < 4; ++e) { r[e] = f2bf(a[e]); r[4 + e] = f2bf(b[e]); }
  ((u16x8*)d)[i] = r;
}

// ---------------- QKV projection: C[4096,3072] = X * Wqkv^T + b ----------------
// BK=64 ping-pong (single barrier/iter), XOR chunk-swizzled LDS, swapped-operand
// MFMA (C^T: lane regs = 4 consecutive n = d) -> u16x4 stores. (b,h,s,d).
__global__ __launch_bounds__(256) void qkv_gemm(
    const u16* __restrict__ A, const u16* __restrict__ Bw,
    const float* __restrict__ bias, u16* __restrict__ Qo,
    u16* __restrict__ Ko, u16* __restrict__ Vo) {
  __shared__ __align__(16) u16 As[2][128 * 64];
  __shared__ __align__(16) u16 Bs[2][128 * 64];

  const int t = threadIdx.x;
  const int lane = t & 63, w = t >> 6;
  const int quad = lane >> 4, col = lane & 15;
  const int wm = w & 1, wn = w >> 1;
  const int m0 = blockIdx.y * 128, n0 = blockIdx.x * 128;

  f32x4 acc[4][4] = {};

  // prologue: stage kt=0
  #pragma unroll
  for (int p = 0; p < 4; ++p) {
    int c = t + 256 * p;                  // 0..1023
    int r = c >> 3, cc = c & 7;
    int so = (cc ^ (r & 7)) * 8;
    gl2lds16(A  + (size_t)(m0 + r) * 1024 + so, &As[0][0] + c * 8);
    gl2lds16(Bw + (size_t)(n0 + r) * 1024 + so, &Bs[0][0] + c * 8);
  }
  __syncthreads();

  for (int kt = 0; kt < 16; ++kt) {
    const u16* Ac = &As[kt & 1][0];
    const u16* Bc = &Bs[kt & 1][0];
    if (kt < 15) {
      const int ko = (kt + 1) * 64;
      u16* An = &As[(kt + 1) & 1][0];
      u16* Bn = &Bs[(kt + 1) & 1][0];
      #pragma unroll
      for (int p = 0; p < 4; ++p) {
        int c = t + 256 * p;
        int r = c >> 3, cc = c & 7;
        int so = ko + ((cc ^ (r & 7)) * 8);
        gl2lds16(A  + (size_t)(m0 + r) * 1024 + so, An + c * 8);
        gl2lds16(Bw + (size_t)(n0 + r) * 1024 + so, Bn + c * 8);
      }
    }

    #pragma unroll
    for (int kk = 0; kk < 2; ++kk) {
      const int e8 = ((kk * 4 + quad) ^ (col & 7)) * 8;
      bf16x8 bfr[4];
      #pragma unroll
      for (int j = 0; j < 4; ++j)
        bfr[j] = ldfrag(Bc + (wn * 64 + j * 16 + col) * 64 + e8);
      #pragma unroll
      for (int i = 0; i < 4; ++i) {
        bf16x8 afr = ldfrag(Ac + (wm * 64 + i * 16 + col) * 64 + e8);
        #pragma unroll
        for (int j = 0; j < 4; ++j)
          acc[i][j] = MFMA16x16x32(bfr[j], afr, acc[i][j]);  // C^T
      }
    }
    __syncthreads();
  }

  const int nb = n0 + wn * 64;              // wave covers one 64-wide head slice
  const int which = nb >> 10;               // 0=q 1=k 2=v (wave-uniform)
  const int h = (nb >> 6) & 15;
  u16* dst = (which == 0) ? Qo : ((which == 1) ? Ko : Vo);
  const float scale = (which == 0) ? 0.125f : 1.0f;  // fold 1/sqrt(64) into Q

  #pragma unroll
  for (int j = 0; j < 4; ++j) {
    const f32x4 b4 = *(const f32x4*)(bias + nb + j * 16 + quad * 4);
    #pragma unroll
    for (int i = 0; i < 4; ++i) {
      const int m = m0 + wm * 64 + i * 16 + col;
      const int bb = m >> 11, s = m & 2047;
      u16x4 vv;
      #pragma unroll
      for (int r = 0; r < 4; ++r) vv[r] = f2bf((acc[i][j][r] + b4[r]) * scale);
      *(u16x4*)(dst + ((size_t)(bb * 16 + h) * 2048 + s) * 64 + j * 16 + quad * 4) = vv;
    }
  }
}

// ---------------- V (b,h,s,d) -> Vt (b,h,d,s) 64x64-tile transpose ----------------
__global__ __launch_bounds__(256) void transpose64(
    const u16* __restrict__ V, u16* __restrict__ Vt) {
  __shared__ u16 tile[64][72];
  const int t = threadIdx.x;
  const int s0 = blockIdx.x * 64;
  const int bh = blockIdx.y;
  const u16* Vb = V + (size_t)bh * (2048 * 64);
  u16* Vtb = Vt + (size_t)bh * (64 * 2048);
  #pragma unroll
  for (int p = 0; p < 2; ++p) {
    int c = t + 256 * p;
    int r = c >> 3, c8 = (c & 7) * 8;
    u16x8 v = *(const u16x8*)(Vb + (size_t)(s0 + r) * 64 + c8);
    #pragma unroll
    for (int e = 0; e < 8; ++e) tile[r][c8 + e] = v[e];
  }
  __syncthreads();
  #pragma unroll
  for (int p = 0; p < 2; ++p) {
    int c = t + 256 * p;
    int dr = c >> 3, c8 = (c & 7) * 8;
    u16x8 v;
    #pragma unroll
    for (int e = 0; e < 8; ++e) v[e] = tile[c8 + e][dr];
    *(u16x8*)(Vtb + (size_t)dr * 2048 + s0 + c8) = v;
  }
}

// ---------------- fused attention (S^T, fat waves, split-K, K+V ping-pong) -------
// 512 threads = 8 fat waves (32 q each; wave pair u shares q, g = key half).
// ONE barrier per 128-key tile. Per iter: masks (oldest vmem -> readable without
// draining staging), sched_barrier, async-stage K+V for kb+1 into the other
// buffers, S^T from LDS, softmax -> Ps (32-key window, XOR 8B-chunk swizzle, two
// PV subpasses reuse it per-wave), PV from LDS. Barrier drain overlaps compute.
// Grid (bh=32, qb=16): same-bh blocks share one XCD's L2 -> K/V pinned.
__global__ __launch_bounds__(512, 4) void attn(
    const u16* __restrict__ Q, const u16* __restrict__ K,
    const u16* __restrict__ Vt, const int* __restrict__ mask,
    u16* __restrict__ AO) {
  __shared__ __align__(16) u16 Ks[2][128 * 64];  // [key][d], XOR 16B-chunk swizzle
  __shared__ __align__(16) u16 Vs[2][64 * 128];  // [d][key], XOR 16B-chunk swizzle
  __shared__ __align__(16) u16 Ps[8][32 * 32];   // per-wave P^T 32q x 32keys, swizzled

  const int t = threadIdx.x;
  const int lane = t & 63, w = t >> 6;
  const int quad = lane >> 4, col = lane & 15;
  const int g = w & 1, u = w >> 1;
  const int bh = blockIdx.x, qb = blockIdx.y;
  const int b = bh >> 4, h = bh & 15;

  const u16* Qh = Q + (size_t)bh * (2048 * 64);
  const u16* Kh = K + (size_t)bh * (2048 * 64);
  const u16* Vh = Vt + (size_t)bh * (64 * 2048);
  const int* mb = mask + b * 2048;

  u16x8 ou;
  #pragma unroll
  for (int e = 0; e < 8; ++e) ou[e] = 0x3F80;    // bf16 1.0
  const bf16x8 ones = __builtin_bit_cast(bf16x8, ou);

  const int qw = qb * 128 + u * 32;              // wave-pair's first q
  const int keyg = g * 64;                       // this wave's key half

  bf16x8 aQ[2][2];
  #pragma unroll
  for (int ct = 0; ct < 2; ++ct) {
    #pragma unroll
    for (int kh = 0; kh < 2; ++kh)
      aQ[ct][kh] = ldfrag(Qh + (size_t)(qw + ct * 16 + col) * 64 + kh * 32 + quad * 8);
  }

  f32x4 o[2][4] = {};
  f32x4 lacc[2] = {};
  u16* Pw = &Ps[w][0];

  // prologue: stage tile 0 (K and V)
  #pragma unroll
  for (int p = 0; p < 2; ++p) {
    int c = t + 512 * p;
    int kr = c >> 3, kc = c & 7;
    gl2lds16(Kh + (size_t)kr * 64 + ((kc ^ (kr & 7)) * 8), &Ks[0][0] + c * 8);
    int vr = c >> 4, vc = c & 15;
    gl2lds16(Vh + (size_t)vr * 2048 + ((vc ^ (vr & 15)) * 8), &Vs[0][0] + c * 8);
  }
  __syncthreads();

  for (int kb = 0; kb < 16; ++kb) {
    const int key0 = kb * 128;
    const u16* Kc = &Ks[kb & 1][0];
    const u16* Vc = &Vs[kb & 1][0];

    // 1) mask loads FIRST (older than staging in vmcnt order)
    int4 m4[4];
    #pragma unroll
    for (int jj = 0; jj < 4; ++jj)
      m4[jj] = *(const int4*)(mb + key0 + keyg + jj * 16 + quad * 4);
    __builtin_amdgcn_sched_barrier(0);

    // 2) async-stage next K+V tiles into the other buffers
    if (kb < 15) {
      u16* Kn = &Ks[(kb + 1) & 1][0];
      u16* Vn = &Vs[(kb + 1) & 1][0];
      #pragma unroll
      for (int p = 0; p < 2; ++p) {
        int c = t + 512 * p;
        int kr = c >> 3, kc = c & 7;
        gl2lds16(Kh + (size_t)(key0 + 128 + kr) * 64 + ((kc ^ (kr & 7)) * 8), Kn + c * 8);
        int vr = c >> 4, vc = c & 15;
        gl2lds16(Vh + (size_t)vr * 2048 + key0 + 128 + ((vc ^ (vr & 15)) * 8), Vn + c * 8);
      }
    }

    // 3) S^T = K Q^T (LDS only; no vmem dependency)
    f32x4 sc[2][4] = {};
    #pragma unroll
    for (int j = 0; j < 4; ++j) {
      #pragma unroll
      for (int kh = 0; kh < 2; ++kh) {
        bf16x8 ak = ldfrag(Kc + (keyg + j * 16 + col) * 64 + (((kh * 4 + quad) ^ (col & 7)) * 8));
        sc[0][j] = MFMA16x16x32(ak, aQ[0][kh], sc[0][j]);
        sc[1][j] = MFMA16x16x32(ak, aQ[1][kh], sc[1][j]);
      }
    }

    uint32_t M[4][2];
    #pragma unroll
    for (int jj = 0; jj < 4; ++jj) {
      M[jj][0] = (m4[jj].x ? 0x0000FFFFu : 0u) | (m4[jj].y ? 0xFFFF0000u : 0u);
      M[jj][1] = (m4[jj].z ? 0x0000FFFFu : 0u) | (m4[jj].w ? 0xFFFF0000u : 0u);
    }

    // 4) two 32-key subpasses: softmax -> Ps, then PV (per-wave Ps reuse)
    #pragma unroll
    for (int sp = 0; sp < 2; ++sp) {
      #pragma unroll
      for (int jj = 0; jj < 2; ++jj) {
        const int j = sp * 2 + jj;
        #pragma unroll
        for (int ct = 0; ct < 2; ++ct) {
          uint2 pk;
          pk.x = pktrunc(__expf(sc[ct][j][0]), __expf(sc[ct][j][1])) & M[j][0];
          pk.y = pktrunc(__expf(sc[ct][j][2]), __expf(sc[ct][j][3])) & M[j][1];
          const int q = ct * 16 + col;
          const int s = (jj * 4 + quad) ^ (q & 7);   // 8B-chunk XOR swizzle
          *(uint2*)(Pw + q * 32 + s * 4) = pk;
        }
      }

      // PV over this 32-key window; l by MFMA with ones
      bf16x8 bP0 = ldfrag2b(Pw + col * 32 + (((quad * 2) ^ (col & 7)) * 4),
                            Pw + col * 32 + (((quad * 2 + 1) ^ (col & 7)) * 4));
      bf16x8 bP1 = ldfrag2b(Pw + (16 + col) * 32 + (((quad * 2) ^ (col & 7)) * 4),
                            Pw + (16 + col) * 32 + (((quad * 2 + 1) ^ (col & 7)) * 4));
      lacc[0] = MFMA16x16x32(ones, bP0, lacc[0]);
      lacc[1] = MFMA16x16x32(ones, bP1, lacc[1]);
      const int win = g * 2 + sp;                    // 32-key window 0..3 in tile
      #pragma unroll
      for (int dt = 0; dt < 4; ++dt) {
        bf16x8 av = ldfrag(Vc + (dt * 16 + col) * 128 + (((win * 4 + quad) ^ col) * 8));
        o[0][dt] = MFMA16x16x32(av, bP0, o[0][dt]);
        o[1][dt] = MFMA16x16x32(av, bP1, o[1][dt]);
      }
    }

    __syncthreads();   // single barrier: staging drained (overlapped by compute)
  }

  // combine wave-pair partials (additive; exchange via dead Ks/Vs buffers)
  float* Ro = (float*)(&Ks[0][0]) + u * 2048 + lane * 32;   // 32 f32/lane
  float* Rl = (float*)(&Vs[0][0]) + u * 128 + lane * 2;
  if (g == 1) {
    #pragma unroll
    for (int ct = 0; ct < 2; ++ct)
      #pragma unroll
      for (int dt = 0; dt < 4; ++dt)
        *(f32x4*)(Ro + ((ct * 4 + dt) ^ (lane & 7)) * 4) = o[ct][dt];
    Rl[0] = lacc[0][0]; Rl[1] = lacc[1][0];
  }
  __syncthreads();
  if (g == 0) {
    float rl[2];
    #pragma unroll
    for (int ct = 0; ct < 2; ++ct) {
      #pragma unroll
      for (int dt = 0; dt < 4; ++dt)
        o[ct][dt] += *(const f32x4*)(Ro + ((ct * 4 + dt) ^ (lane & 7)) * 4);
      rl[ct] = 1.0f / (lacc[ct][0] + Rl[ct]);
    }
    #pragma unroll
    for (int ct = 0; ct < 2; ++ct) {
      const int q = qw + ct * 16 + col;
      #pragma unroll
      for (int dt = 0; dt < 4; ++dt) {
        u16x4 v;
        #pragma unroll
        for (int r = 0; r < 4; ++r) v[r] = f2bf(o[ct][dt][r] * rl[ct]);
        *(u16x4*)(AO + (size_t)(b * 2048 + q) * 1024 + h * 64 + dt * 16 + quad * 4) = v;
      }
    }
  }
}

// ---------------- output projection: out = AO * Wout^T + bout (fp32 out) ----------------
// 128m x 64n tile (grid 512 -> 2 blocks/CU), BK=64 ping-pong, ONE barrier/iter.
__global__ __launch_bounds__(256) void proj_gemm(
    const u16* __restrict__ A, const u16* __restrict__ Bw,
    const float* __restrict__ bias, float* __restrict__ out) {
  __shared__ __align__(16) u16 As[2][128 * 64];
  __shared__ __align__(16) u16 Bs[2][64 * 64];

  const int t = threadIdx.x;
  const int lane = t & 63, w = t >> 6;
  const int quad = lane >> 4, col = lane & 15;
  const int wm = w & 1, wn = w >> 1;
  const int m0 = blockIdx.y * 128, n0 = blockIdx.x * 64;

  f32x4 acc[4][2] = {};

  // prologue: stage kt=0
  #pragma unroll
  for (int p = 0; p < 4; ++p) {
    int c = t + 256 * p;
    int r = c >> 3, cc = c & 7;
    gl2lds16(A + (size_t)(m0 + r) * 1024 + ((cc ^ (r & 7)) * 8), &As[0][0] + c * 8);
  }
  #pragma unroll
  for (int p = 0; p < 2; ++p) {
    int c = t + 256 * p;
    int r = c >> 3, cc = c & 7;
    gl2lds16(Bw + (size_t)(n0 + r) * 1024 + ((cc ^ (r & 7)) * 8), &Bs[0][0] + c * 8);
  }
  __syncthreads();

  for (int kt = 0; kt < 16; ++kt) {
    const u16* Ac = &As[kt & 1][0];
    const u16* Bc = &Bs[kt & 1][0];
    if (kt < 15) {
      const int ko = (kt + 1) * 64;
      u16* An = &As[(kt + 1) & 1][0];
      u16* Bn = &Bs[(kt + 1) & 1][0];
      #pragma unroll
      for (int p = 0; p < 4; ++p) {
        int c = t + 256 * p;
        int r = c >> 3, cc = c & 7;
        gl2lds16(A + (size_t)(m0 + r) * 1024 + ko + ((cc ^ (r & 7)) * 8), An + c * 8);
      }
      #pragma unroll
      for (int p = 0; p < 2; ++p) {
        int c = t + 256 * p;
        int r = c >> 3, cc = c & 7;
        gl2lds16(Bw + (size_t)(n0 + r) * 1024 + ko + ((cc ^ (r & 7)) * 8), Bn + c * 8);
      }
    }

    #pragma unroll
    for (int kk = 0; kk < 2; ++kk) {
      const int e8 = ((kk * 4 + quad) ^ (col & 7)) * 8;
      bf16x8 bfr[2];
      #pragma unroll
      for (int j = 0; j < 2; ++j)
        bfr[j] = ldfrag(Bc + (wn * 32 + j * 16 + col) * 64 + e8);
      #pragma unroll
      for (int i = 0; i < 4; ++i) {
        bf16x8 afr = ldfrag(Ac + (wm * 64 + i * 16 + col) * 64 + e8);
        #pragma unroll
        for (int j = 0; j < 2; ++j)
          acc[i][j] = MFMA16x16x32(bfr[j], afr, acc[i][j]);  // C^T
      }
    }
    __syncthreads();
  }

  const int nb = n0 + wn * 32;
  #pragma unroll
  for (int j = 0; j < 2; ++j) {
    const f32x4 b4 = *(const f32x4*)(bias + nb + j * 16 + quad * 4);
    #pragma unroll
    for (int i = 0; i < 4; ++i) {
      const int m = m0 + wm * 64 + i * 16 + col;
      f32x4 vv = acc[i][j] + b4;
      *(f32x4*)(out + (size_t)m * 1024 + nb + j * 16 + quad * 4) = vv;
    }
  }
}

extern "C" void kernel_launch(void* const* d_in, const int* in_sizes, int n_in,
                              void* d_out, int out_size, void* d_ws, size_t ws_size,
                              hipStream_t stream) {
  (void)in_sizes; (void)n_in; (void)out_size; (void)ws_size;
  const float* x    = (const float*)d_in[0];
  const int*   mask = (const int*)d_in[1];
  const float* Wqkv = (const float*)d_in[2];
  const float* bqkv = (const float*)d_in[3];
  const float* Wout = (const float*)d_in[4];
  const float* bout = (const float*)d_in[5];
  float* out = (float*)d_out;
  char* ws = (char*)d_ws;

  u16* Xb  = (u16*)(ws);                         // 8 MiB (reused as AO later)
  u16* Wqb = (u16*)(ws + ((size_t)8  << 20));    // 6 MiB
  u16* Wob = (u16*)(ws + ((size_t)14 << 20));    // 2 MiB
  u16* Qb  = (u16*)(ws + ((size_t)16 << 20));    // 8 MiB
  u16* Kb  = (u16*)(ws + ((size_t)24 << 20));    // 8 MiB
  u16* Vb  = (u16*)(ws + ((size_t)32 << 20));    // 8 MiB
  u16* Vtb = (u16*)(ws + ((size_t)40 << 20));    // 8 MiB  (total 48 MiB)
  u16* AO  = Xb;  // X is dead after qkv_gemm

  convert3<<<dim3(4096), dim3(256), 0, stream>>>(x, Wqkv, Wout, Xb, Wqb, Wob);
  qkv_gemm<<<dim3(24, 32), dim3(256), 0, stream>>>(Xb, Wqb, bqkv, Qb, Kb, Vb);
  transpose64<<<dim3(32, 32), dim3(256), 0, stream>>>(Vb, Vtb);
  attn<<<dim3(32, 16), dim3(512), 0, stream>>>(Qb, Kb, Vtb, mask, AO);
  proj_gemm<<<dim3(16, 32), dim3(256), 0, stream>>>(AO, Wob, bout, out);
}

// Round 9
// 203.241 us; speedup vs baseline: 1.0992x; 1.0183x over previous
//
#include <hip/hip_runtime.h>
#include <stdint.h>

typedef unsigned short u16;
typedef __bf16    bf16x8 __attribute__((ext_vector_type(8)));
typedef u16       u16x8  __attribute__((ext_vector_type(8)));
typedef u16       u16x4  __attribute__((ext_vector_type(4)));
typedef float     f32x4  __attribute__((ext_vector_type(4)));
typedef uint32_t  u32x4  __attribute__((ext_vector_type(4)));

#define MFMA16x16x32(a, b, c) __builtin_amdgcn_mfma_f32_16x16x32_bf16((a), (b), (c), 0, 0, 0)

__device__ __forceinline__ u16 f2bf(float f) {
  uint32_t u = __float_as_uint(f);
  u += 0x7FFFu + ((u >> 16) & 1u);   // RNE
  return (u16)(u >> 16);
}

// pack hi16(a), hi16(b) -> one dword via v_perm (truncation toward zero; p>=0)
__device__ __forceinline__ uint32_t pktrunc(float a, float b) {
  return __builtin_amdgcn_perm(__float_as_uint(b), __float_as_uint(a), 0x07060302u);
}

__device__ __forceinline__ bf16x8 ldfrag(const u16* p) {
  return __builtin_bit_cast(bf16x8, *(const u16x8*)p);
}

// fragment from two separate 8B LDS reads (XOR-swizzled chunks)
__device__ __forceinline__ bf16x8 ldfrag2b(const u16* p0, const u16* p1) {
  uint2 a = *(const uint2*)p0;
  uint2 b = *(const uint2*)(p1);
  u32x4 t; t[0] = a.x; t[1] = a.y; t[2] = b.x; t[3] = b.y;
  return __builtin_bit_cast(bf16x8, t);
}

// async global->LDS, 16B per lane. LDS dest must be wave-uniform base + lane*16.
__device__ __forceinline__ void gl2lds16(const u16* g, u16* l) {
  __builtin_amdgcn_global_load_lds(
      (__attribute__((address_space(1))) void*)g,
      (__attribute__((address_space(3))) void*)l, 16, 0, 0);
}

// ---------------- fp32 -> bf16 conversion of x, Wqkv, Wout ----------------
__global__ __launch_bounds__(256) void convert3(
    const float* __restrict__ x, const float* __restrict__ wq,
    const float* __restrict__ wo, u16* __restrict__ xb,
    u16* __restrict__ wqb, u16* __restrict__ wob) {
  const int NX = (4096 * 1024) / 8;
  const int NQ = (3072 * 1024) / 8;
  int i = blockIdx.x * 256 + threadIdx.x;   // exactly covers NX+NQ+NO
  const float* s;
  u16* d;
  if (i < NX)           { s = x;  d = xb;  }
  else if (i < NX + NQ) { s = wq; d = wqb; i -= NX; }
  else                  { s = wo; d = wob; i -= NX + NQ; }
  f32x4 a = ((const f32x4*)s)[2 * (size_t)i];
  f32x4 b = ((const f32x4*)s)[2 * (size_t)i + 1];
  u16x8 r;
  #pragma unroll
  for (int e = 0; e < 4; ++e) { r[e] = f2bf(a[e]); r[4 + e] = f2bf(b[e]); }
  ((u16x8*)d)[i] = r;
}

// ---------------- QKV projection: C[4096,3072] = X * Wqkv^T + b ----------------
// BK=64 single-buffer (32 KB -> 3 blocks/CU), XOR chunk-swizzled LDS,
// swapped-operand MFMA (C^T) -> u16x4 stores. XCD-aware 1D grid: xcd = l&7 owns
// n-panels [3*xcd, 3*xcd+3) so each XCD keeps its 0.75 MB B-panel L2-hot.
// Q scaled by 0.125*log2(e) (softmax uses exp2 downstream).
__global__ __launch_bounds__(256) void qkv_gemm(
    const u16* __restrict__ A, const u16* __restrict__ Bw,
    const float* __restrict__ bias, u16* __restrict__ Qo,
    u16* __restrict__ Ko, u16* __restrict__ Vo) {
  __shared__ __align__(16) u16 As[128 * 64];
  __shared__ __align__(16) u16 Bs[128 * 64];

  const int t = threadIdx.x;
  const int lane = t & 63, w = t >> 6;
  const int quad = lane >> 4, col = lane & 15;
  const int wm = w & 1, wn = w >> 1;
  const int l = blockIdx.x;
  const int xcd = l & 7, kk2 = l >> 3;
  const int n0 = (xcd * 3 + (kk2 % 3)) * 128;
  const int m0 = (kk2 / 3) * 128;

  f32x4 acc[4][4] = {};

  for (int kt = 0; kt < 16; ++kt) {
    const int ko = kt * 64;
    __syncthreads();
    #pragma unroll
    for (int p = 0; p < 4; ++p) {
      int c = t + 256 * p;                  // 0..1023
      int r = c >> 3, cc = c & 7;
      int so = ko + ((cc ^ (r & 7)) * 8);
      gl2lds16(A  + (size_t)(m0 + r) * 1024 + so, As + c * 8);
      gl2lds16(Bw + (size_t)(n0 + r) * 1024 + so, Bs + c * 8);
    }
    __syncthreads();

    #pragma unroll
    for (int kk = 0; kk < 2; ++kk) {
      const int e8 = ((kk * 4 + quad) ^ (col & 7)) * 8;
      bf16x8 bfr[4];
      #pragma unroll
      for (int j = 0; j < 4; ++j)
        bfr[j] = ldfrag(Bs + (wn * 64 + j * 16 + col) * 64 + e8);
      #pragma unroll
      for (int i = 0; i < 4; ++i) {
        bf16x8 afr = ldfrag(As + (wm * 64 + i * 16 + col) * 64 + e8);
        #pragma unroll
        for (int j = 0; j < 4; ++j)
          acc[i][j] = MFMA16x16x32(bfr[j], afr, acc[i][j]);  // C^T
      }
    }
  }

  const int nb = n0 + wn * 64;              // wave covers one 64-wide head slice
  const int which = nb >> 10;               // 0=q 1=k 2=v (wave-uniform)
  const int h = (nb >> 6) & 15;
  u16* dst = (which == 0) ? Qo : ((which == 1) ? Ko : Vo);
  // fold 1/sqrt(64) AND log2(e) into Q (downstream softmax uses exp2)
  const float scale = (which == 0) ? 0.125f * 1.44269504088896f : 1.0f;

  #pragma unroll
  for (int j = 0; j < 4; ++j) {
    const f32x4 b4 = *(const f32x4*)(bias + nb + j * 16 + quad * 4);
    #pragma unroll
    for (int i = 0; i < 4; ++i) {
      const int m = m0 + wm * 64 + i * 16 + col;
      const int bb = m >> 11, s = m & 2047;
      u16x4 vv;
      #pragma unroll
      for (int r = 0; r < 4; ++r) vv[r] = f2bf((acc[i][j][r] + b4[r]) * scale);
      *(u16x4*)(dst + ((size_t)(bb * 16 + h) * 2048 + s) * 64 + j * 16 + quad * 4) = vv;
    }
  }
}

// ---------------- V (b,h,s,d) -> Vt (b,h,d,s) 64x64-tile transpose ----------------
__global__ __launch_bounds__(256) void transpose64(
    const u16* __restrict__ V, u16* __restrict__ Vt) {
  __shared__ u16 tile[64][72];
  const int t = threadIdx.x;
  const int s0 = blockIdx.x * 64;
  const int bh = blockIdx.y;
  const u16* Vb = V + (size_t)bh * (2048 * 64);
  u16* Vtb = Vt + (size_t)bh * (64 * 2048);
  #pragma unroll
  for (int p = 0; p < 2; ++p) {
    int c = t + 256 * p;
    int r = c >> 3, c8 = (c & 7) * 8;
    u16x8 v = *(const u16x8*)(Vb + (size_t)(s0 + r) * 64 + c8);
    #pragma unroll
    for (int e = 0; e < 8; ++e) tile[r][c8 + e] = v[e];
  }
  __syncthreads();
  #pragma unroll
  for (int p = 0; p < 2; ++p) {
    int c = t + 256 * p;
    int dr = c >> 3, c8 = (c & 7) * 8;
    u16x8 v;
    #pragma unroll
    for (int e = 0; e < 8; ++e) v[e] = tile[c8 + e][dr];
    *(u16x8*)(Vtb + (size_t)dr * 2048 + s0 + c8) = v;
  }
}

// ---------------- fused attention (S^T, fat waves, split-K, K+V ping-pong) -------
// 512 threads = 8 fat waves (32 q each; wave pair u shares q, g = key half).
// ONE barrier per 128-key tile (staging drain overlapped by compute).
// Ps chunk swizzle includes q bit 3 (psw) -> bank-pair-uniform b64 accesses.
// Softmax numerators via exp2 (log2e pre-folded into Q scale).
// Grid (bh=32, qb=16): same-bh blocks share one XCD's L2 -> K/V pinned.
__global__ __launch_bounds__(512, 4) void attn(
    const u16* __restrict__ Q, const u16* __restrict__ K,
    const u16* __restrict__ Vt, const int* __restrict__ mask,
    u16* __restrict__ AO) {
  __shared__ __align__(16) u16 Ks[2][128 * 64];  // [key][d], XOR 16B-chunk swizzle
  __shared__ __align__(16) u16 Vs[2][64 * 128];  // [d][key], XOR 16B-chunk swizzle
  __shared__ __align__(16) u16 Ps[8][32 * 32];   // per-wave P^T 32q x 32keys, swizzled

  const int t = threadIdx.x;
  const int lane = t & 63, w = t >> 6;
  const int quad = lane >> 4, col = lane & 15;
  const int g = w & 1, u = w >> 1;
  const int bh = blockIdx.x, qb = blockIdx.y;
  const int b = bh >> 4, h = bh & 15;

  const u16* Qh = Q + (size_t)bh * (2048 * 64);
  const u16* Kh = K + (size_t)bh * (2048 * 64);
  const u16* Vh = Vt + (size_t)bh * (64 * 2048);
  const int* mb = mask + b * 2048;

  u16x8 ou;
  #pragma unroll
  for (int e = 0; e < 8; ++e) ou[e] = 0x3F80;    // bf16 1.0
  const bf16x8 ones = __builtin_bit_cast(bf16x8, ou);

  const int qw = qb * 128 + u * 32;              // wave-pair's first q
  const int keyg = g * 64;                       // this wave's key half
  const int psw = (col & 7) ^ ((col >> 3) << 2); // Ps chunk swizzle (q bits 0..3)

  bf16x8 aQ[2][2];
  #pragma unroll
  for (int ct = 0; ct < 2; ++ct) {
    #pragma unroll
    for (int kh = 0; kh < 2; ++kh)
      aQ[ct][kh] = ldfrag(Qh + (size_t)(qw + ct * 16 + col) * 64 + kh * 32 + quad * 8);
  }

  f32x4 o[2][4] = {};
  f32x4 lacc[2] = {};
  u16* Pw = &Ps[w][0];

  // prologue: stage tile 0 (K and V)
  #pragma unroll
  for (int p = 0; p < 2; ++p) {
    int c = t + 512 * p;
    int kr = c >> 3, kc = c & 7;
    gl2lds16(Kh + (size_t)kr * 64 + ((kc ^ (kr & 7)) * 8), &Ks[0][0] + c * 8);
    int vr = c >> 4, vc = c & 15;
    gl2lds16(Vh + (size_t)vr * 2048 + ((vc ^ (vr & 15)) * 8), &Vs[0][0] + c * 8);
  }
  __syncthreads();

  for (int kb = 0; kb < 16; ++kb) {
    const int key0 = kb * 128;
    const u16* Kc = &Ks[kb & 1][0];
    const u16* Vc = &Vs[kb & 1][0];

    // 1) mask loads FIRST (older than staging in vmcnt order)
    int4 m4[4];
    #pragma unroll
    for (int jj = 0; jj < 4; ++jj)
      m4[jj] = *(const int4*)(mb + key0 + keyg + jj * 16 + quad * 4);
    __builtin_amdgcn_sched_barrier(0);

    // 2) async-stage next K+V tiles into the other buffers
    if (kb < 15) {
      u16* Kn = &Ks[(kb + 1) & 1][0];
      u16* Vn = &Vs[(kb + 1) & 1][0];
      #pragma unroll
      for (int p = 0; p < 2; ++p) {
        int c = t + 512 * p;
        int kr = c >> 3, kc = c & 7;
        gl2lds16(Kh + (size_t)(key0 + 128 + kr) * 64 + ((kc ^ (kr & 7)) * 8), Kn + c * 8);
        int vr = c >> 4, vc = c & 15;
        gl2lds16(Vh + (size_t)vr * 2048 + key0 + 128 + ((vc ^ (vr & 15)) * 8), Vn + c * 8);
      }
    }

    // 3) S^T = K Q^T (LDS only; no vmem dependency)
    f32x4 sc[2][4] = {};
    #pragma unroll
    for (int j = 0; j < 4; ++j) {
      #pragma unroll
      for (int kh = 0; kh < 2; ++kh) {
        bf16x8 ak = ldfrag(Kc + (keyg + j * 16 + col) * 64 + (((kh * 4 + quad) ^ (col & 7)) * 8));
        sc[0][j] = MFMA16x16x32(ak, aQ[0][kh], sc[0][j]);
        sc[1][j] = MFMA16x16x32(ak, aQ[1][kh], sc[1][j]);
      }
    }

    uint32_t M[4][2];
    #pragma unroll
    for (int jj = 0; jj < 4; ++jj) {
      M[jj][0] = (m4[jj].x ? 0x0000FFFFu : 0u) | (m4[jj].y ? 0xFFFF0000u : 0u);
      M[jj][1] = (m4[jj].z ? 0x0000FFFFu : 0u) | (m4[jj].w ? 0xFFFF0000u : 0u);
    }

    // 4) two 32-key subpasses: softmax -> Ps, then PV (per-wave Ps reuse)
    #pragma unroll
    for (int sp = 0; sp < 2; ++sp) {
      #pragma unroll
      for (int jj = 0; jj < 2; ++jj) {
        const int j = sp * 2 + jj;
        #pragma unroll
        for (int ct = 0; ct < 2; ++ct) {
          uint2 pk;
          pk.x = pktrunc(__builtin_exp2f(sc[ct][j][0]), __builtin_exp2f(sc[ct][j][1])) & M[j][0];
          pk.y = pktrunc(__builtin_exp2f(sc[ct][j][2]), __builtin_exp2f(sc[ct][j][3])) & M[j][1];
          const int q = ct * 16 + col;
          const int s = (jj * 4 + quad) ^ psw;     // 8B-chunk XOR swizzle (bank-uniform)
          *(uint2*)(Pw + q * 32 + s * 4) = pk;
        }
      }

      // PV over this 32-key window; l by MFMA with ones
      bf16x8 bP0 = ldfrag2b(Pw + col * 32 + (((quad * 2) ^ psw) * 4),
                            Pw + col * 32 + (((quad * 2 + 1) ^ psw) * 4));
      bf16x8 bP1 = ldfrag2b(Pw + (16 + col) * 32 + (((quad * 2) ^ psw) * 4),
                            Pw + (16 + col) * 32 + (((quad * 2 + 1) ^ psw) * 4));
      lacc[0] = MFMA16x16x32(ones, bP0, lacc[0]);
      lacc[1] = MFMA16x16x32(ones, bP1, lacc[1]);
      const int win = g * 2 + sp;                    // 32-key window 0..3 in tile
      #pragma unroll
      for (int dt = 0; dt < 4; ++dt) {
        bf16x8 av = ldfrag(Vc + (dt * 16 + col) * 128 + (((win * 4 + quad) ^ col) * 8));
        o[0][dt] = MFMA16x16x32(av, bP0, o[0][dt]);
        o[1][dt] = MFMA16x16x32(av, bP1, o[1][dt]);
      }
    }

    __syncthreads();   // single barrier: staging drained (overlapped by compute)
  }

  // combine wave-pair partials (additive; exchange via dead Ks/Vs buffers)
  float* Ro = (float*)(&Ks[0][0]) + u * 2048 + lane * 32;   // 32 f32/lane
  float* Rl = (float*)(&Vs[0][0]) + u * 128 + lane * 2;
  if (g == 1) {
    #pragma unroll
    for (int ct = 0; ct < 2; ++ct)
      #pragma unroll
      for (int dt = 0; dt < 4; ++dt)
        *(f32x4*)(Ro + ((ct * 4 + dt) ^ (lane & 7)) * 4) = o[ct][dt];
    Rl[0] = lacc[0][0]; Rl[1] = lacc[1][0];
  }
  __syncthreads();
  if (g == 0) {
    float rl[2];
    #pragma unroll
    for (int ct = 0; ct < 2; ++ct) {
      #pragma unroll
      for (int dt = 0; dt < 4; ++dt)
        o[ct][dt] += *(const f32x4*)(Ro + ((ct * 4 + dt) ^ (lane & 7)) * 4);
      rl[ct] = 1.0f / (lacc[ct][0] + Rl[ct]);
    }
    #pragma unroll
    for (int ct = 0; ct < 2; ++ct) {
      const int q = qw + ct * 16 + col;
      #pragma unroll
      for (int dt = 0; dt < 4; ++dt) {
        u16x4 v;
        #pragma unroll
        for (int r = 0; r < 4; ++r) v[r] = f2bf(o[ct][dt][r] * rl[ct]);
        *(u16x4*)(AO + (size_t)(b * 2048 + q) * 1024 + h * 64 + dt * 16 + quad * 4) = v;
      }
    }
  }
}

// ---------------- output projection: out = AO * Wout^T + bout (fp32 out) ----------------
// 128m x 64n tile, BK=64 ping-pong, ONE barrier/iter. XCD-aware 1D grid:
// xcd = l&7 owns n-panels [2*xcd, 2*xcd+2) -> 0.25 MB B-panel L2-hot per XCD.
__global__ __launch_bounds__(256) void proj_gemm(
    const u16* __restrict__ A, const u16* __restrict__ Bw,
    const float* __restrict__ bias, float* __restrict__ out) {
  __shared__ __align__(16) u16 As[2][128 * 64];
  __shared__ __align__(16) u16 Bs[2][64 * 64];

  const int t = threadIdx.x;
  const int lane = t & 63, w = t >> 6;
  const int quad = lane >> 4, col = lane & 15;
  const int wm = w & 1, wn = w >> 1;
  const int l = blockIdx.x;
  const int xcd = l & 7, kk2 = l >> 3;
  const int n0 = (xcd * 2 + (kk2 & 1)) * 64;
  const int m0 = (kk2 >> 1) * 128;

  f32x4 acc[4][2] = {};

  // prologue: stage kt=0
  #pragma unroll
  for (int p = 0; p < 4; ++p) {
    int c = t + 256 * p;
    int r = c >> 3, cc = c & 7;
    gl2lds16(A + (size_t)(m0 + r) * 1024 + ((cc ^ (r & 7)) * 8), &As[0][0] + c * 8);
  }
  #pragma unroll
  for (int p = 0; p < 2; ++p) {
    int c = t + 256 * p;
    int r = c >> 3, cc = c & 7;
    gl2lds16(Bw + (size_t)(n0 + r) * 1024 + ((cc ^ (r & 7)) * 8), &Bs[0][0] + c * 8);
  }
  __syncthreads();

  for (int kt = 0; kt < 16; ++kt) {
    const u16* Ac = &As[kt & 1][0];
    const u16* Bc = &Bs[kt & 1][0];
    if (kt < 15) {
      const int ko = (kt + 1) * 64;
      u16* An = &As[(kt + 1) & 1][0];
      u16* Bn = &Bs[(kt + 1) & 1][0];
      #pragma unroll
      for (int p = 0; p < 4; ++p) {
        int c = t + 256 * p;
        int r = c >> 3, cc = c & 7;
        gl2lds16(A + (size_t)(m0 + r) * 1024 + ko + ((cc ^ (r & 7)) * 8), An + c * 8);
      }
      #pragma unroll
      for (int p = 0; p < 2; ++p) {
        int c = t + 256 * p;
        int r = c >> 3, cc = c & 7;
        gl2lds16(Bw + (size_t)(n0 + r) * 1024 + ko + ((cc ^ (r & 7)) * 8), Bn + c * 8);
      }
    }

    #pragma unroll
    for (int kk = 0; kk < 2; ++kk) {
      const int e8 = ((kk * 4 + quad) ^ (col & 7)) * 8;
      bf16x8 bfr[2];
      #pragma unroll
      for (int j = 0; j < 2; ++j)
        bfr[j] = ldfrag(Bc + (wn * 32 + j * 16 + col) * 64 + e8);
      #pragma unroll
      for (int i = 0; i < 4; ++i) {
        bf16x8 afr = ldfrag(Ac + (wm * 64 + i * 16 + col) * 64 + e8);
        #pragma unroll
        for (int j = 0; j < 2; ++j)
          acc[i][j] = MFMA16x16x32(bfr[j], afr, acc[i][j]);  // C^T
      }
    }
    __syncthreads();
  }

  const int nb = n0 + wn * 32;
  #pragma unroll
  for (int j = 0; j < 2; ++j) {
    const f32x4 b4 = *(const f32x4*)(bias + nb + j * 16 + quad * 4);
    #pragma unroll
    for (int i = 0; i < 4; ++i) {
      const int m = m0 + wm * 64 + i * 16 + col;
      f32x4 vv = acc[i][j] + b4;
      *(f32x4*)(out + (size_t)m * 1024 + nb + j * 16 + quad * 4) = vv;
    }
  }
}

extern "C" void kernel_launch(void* const* d_in, const int* in_sizes, int n_in,
                              void* d_out, int out_size, void* d_ws, size_t ws_size,
                              hipStream_t stream) {
  (void)in_sizes; (void)n_in; (void)out_size; (void)ws_size;
  const float* x    = (const float*)d_in[0];
  const int*   mask = (const int*)d_in[1];
  const float* Wqkv = (const float*)d_in[2];
  const float* bqkv = (const float*)d_in[3];
  const float* Wout = (const float*)d_in[4];
  const float* bout = (const float*)d_in[5];
  float* out = (float*)d_out;
  char* ws = (char*)d_ws;

  u16* Xb  = (u16*)(ws);                         // 8 MiB (reused as AO later)
  u16* Wqb = (u16*)(ws + ((size_t)8  << 20));    // 6 MiB
  u16* Wob = (u16*)(ws + ((size_t)14 << 20));    // 2 MiB
  u16* Qb  = (u16*)(ws + ((size_t)16 << 20));    // 8 MiB
  u16* Kb  = (u16*)(ws + ((size_t)24 << 20));    // 8 MiB
  u16* Vb  = (u16*)(ws + ((size_t)32 << 20));    // 8 MiB
  u16* Vtb = (u16*)(ws + ((size_t)40 << 20));    // 8 MiB  (total 48 MiB)
  u16* AO  = Xb;  // X is dead after qkv_gemm

  convert3<<<dim3(4096), dim3(256), 0, stream>>>(x, Wqkv, Wout, Xb, Wqb, Wob);
  qkv_gemm<<<dim3(768), dim3(256), 0, stream>>>(Xb, Wqb, bqkv, Qb, Kb, Vb);
  transpose64<<<dim3(32, 32), dim3(256), 0, stream>>>(Vb, Vtb);
  attn<<<dim3(32, 16), dim3(512), 0, stream>>>(Qb, Kb, Vtb, mask, AO);
  proj_gemm<<<dim3(512), dim3(256), 0, stream>>>(AO, Wob, bout, out);
}